// Round 2
// baseline (361.963 us; speedup 1.0000x reference)
//
#include <hip/hip_runtime.h>
#include <math.h>

#define BATCH 16
#define CH    64
#define HH    128
#define WW    128
#define PLANE (HH*WW)          // 16384
#define LROW  144              // padded row stride (8 left + 128 + 8 right)
#define LROWS 138              // padded rows (5 + 128 + 5)
#define OUT0  (BATCH*3*CH*PLANE)  // 50331648
#define SR4   36               // float4 per staged row in k_maxch (144 floats)
#define SROWS 26               // staged rows per 16-row tile (5 + 16 + 5)
#define MBOFF 8192             // float offset of maxbuf in ws
#define MBN   786432           // u64 entries per maxbuf half (16*3*16384)

// ws layout (floats): [0,1024) M ; [1024,2048) ps ; [2048) S ; [3072) Sw ;
// [4096) Sh ; [5120) Scol ; [6144) Srow ; [8192) maxbuf u64[2][786432] (12 MB)

// Order-preserving float<->uint encoding (monotone: a<b  <=>  enc(a)<enc(b))
__device__ __forceinline__ unsigned enc32(float f) {
    unsigned u = __float_as_uint(f);
    return (u & 0x80000000u) ? ~u : (u | 0x80000000u);
}
__device__ __forceinline__ float dec32(unsigned k) {
    unsigned u = (k & 0x80000000u) ? (k ^ 0x80000000u) : ~k;
    return __uint_as_float(u);
}

// ---------------- Kernel 1: per-(b,c) plane: M/ps + the 5 weighted sums -----
// Whole plane staged in LDS (79.5 KiB). No large global writes.
__global__ __launch_bounds__(256) void k_stats(
    const float* __restrict__ x,
    const float* __restrict__ w_bbx, const float* __restrict__ w_width,
    const float* __restrict__ w_width_sh, const float* __restrict__ w_height,
    const float* __restrict__ w_height_sh,
    float* __restrict__ ws) {
    __shared__ float xs[LROWS * LROW];
    __shared__ float red[4 * 5];
    __shared__ float sm[5];
    int bid = blockIdx.x;                  // b*64 + c
    int b = bid >> 6, c = bid & 63;
    (void)b;
    int tid = threadIdx.x;

    // zero-pad whole LDS plane (float4), then fill interior while computing max
    for (int j = tid; j < LROWS * LROW / 4; j += 256)
        ((float4*)xs)[j] = make_float4(0.f, 0.f, 0.f, 0.f);
    __syncthreads();
    const float* xp = x + (size_t)bid * PLANE;
    float m = -INFINITY;
#pragma unroll
    for (int i = 0; i < 16; i++) {
        int idx = i * 256 + tid;           // float4 index in plane
        int p = idx * 4;
        int y = p >> 7, xc = p & 127;
        float4 v = ((const float4*)xp)[idx];
        m = fmaxf(m, fmaxf(fmaxf(v.x, v.y), fmaxf(v.z, v.w)));
        *(float4*)&xs[(y + 5) * LROW + xc + 8] = v;
    }
#pragma unroll
    for (int off = 32; off; off >>= 1) m = fmaxf(m, __shfl_xor(m, off, 64));
    int wid = tid >> 6, lane = tid & 63;
    if (lane == 0) sm[wid] = m;
    __syncthreads();                       // staging done AND sm ready
    if (tid == 0) {
        float mm = fmaxf(fmaxf(sm[0], sm[1]), fmaxf(sm[2], sm[3]));
        float ps = 1.0f / (1.0f + expf(-mm));
        ws[bid] = ps - 0.01f;              // M (consumed by k_maxch)
        ws[1024 + bid] = ps;               // ps
        sm[4] = ps - 0.01f;                // broadcast M
    }
    float wk[11], hk[11];
#pragma unroll
    for (int k = 0; k < 11; k++) {
        wk[k] = w_width[c * 11 + k];
        hk[k] = w_height[c * 11 + k];
    }
    float cb = w_bbx[c];
    float cw = 128.0f * w_width_sh[c] * cb;
    float chs = 128.0f * w_height_sh[c] * cb;
    __syncthreads();
    float M = sm[4];

    float S = 0.f, Sw = 0.f, Sh = 0.f, Scol = 0.f, Srow = 0.f;
    for (int g = 0; g < 16; g++) {
        int idx = g * 256 + tid;
        int p = idx * 4;
        int y = p >> 7, xc = p & 127;
        float4 vx;
        float hx = 0.f, hy = 0.f, hz = 0.f, hw = 0.f;
#pragma unroll
        for (int k = 0; k < 11; k++) {
            float4 v = *(const float4*)&xs[(y + k) * LROW + xc + 8];
            if (k == 5) vx = v;
            hx += v.x * hk[k]; hy += v.y * hk[k];
            hz += v.z * hk[k]; hw += v.w * hk[k];
        }
        float wbuf[20];
        {
            float4 a0 = *(const float4*)&xs[(y + 5) * LROW + xc + 0];
            float4 a1 = *(const float4*)&xs[(y + 5) * LROW + xc + 4];
            float4 a3 = *(const float4*)&xs[(y + 5) * LROW + xc + 12];
            float4 a4 = *(const float4*)&xs[(y + 5) * LROW + xc + 16];
            wbuf[0] = a0.x;  wbuf[1] = a0.y;  wbuf[2] = a0.z;  wbuf[3] = a0.w;
            wbuf[4] = a1.x;  wbuf[5] = a1.y;  wbuf[6] = a1.z;  wbuf[7] = a1.w;
            wbuf[8] = vx.x;  wbuf[9] = vx.y;  wbuf[10] = vx.z; wbuf[11] = vx.w;
            wbuf[12] = a3.x; wbuf[13] = a3.y; wbuf[14] = a3.z; wbuf[15] = a3.w;
            wbuf[16] = a4.x; wbuf[17] = a4.y; wbuf[18] = a4.z; wbuf[19] = a4.w;
        }
        float wo[4];
#pragma unroll
        for (int j = 0; j < 4; j++) {
            float acc = 0.f;
#pragma unroll
            for (int k = 0; k < 11; k++) acc += wbuf[j + 3 + k] * wk[k];
            wo[j] = acc * cw;
        }
        float ho[4] = {hx * chs, hy * chs, hz * chs, hw * chs};
        float xv[4] = {vx.x, vx.y, vx.z, vx.w};
        float sc[4];
#pragma unroll
        for (int j = 0; j < 4; j++) {
            float sx = 1.0f / (1.0f + expf(-xv[j]));
            sc[j] = (sx > M) ? xv[j] : 0.0f;
        }
        float s4 = sc[0] + sc[1] + sc[2] + sc[3];
        S += s4;
        Srow += (float)y * s4;
#pragma unroll
        for (int j = 0; j < 4; j++) {
            Sw += wo[j] * sc[j];
            Sh += ho[j] * sc[j];
            Scol += (float)(xc + j) * sc[j];
        }
    }
#pragma unroll
    for (int off = 32; off; off >>= 1) {
        S    += __shfl_xor(S, off, 64);
        Sw   += __shfl_xor(Sw, off, 64);
        Sh   += __shfl_xor(Sh, off, 64);
        Scol += __shfl_xor(Scol, off, 64);
        Srow += __shfl_xor(Srow, off, 64);
    }
    if (lane == 0) {
        red[wid * 5 + 0] = S;   red[wid * 5 + 1] = Sw;
        red[wid * 5 + 2] = Sh;  red[wid * 5 + 3] = Scol;
        red[wid * 5 + 4] = Srow;
    }
    __syncthreads();
    if (tid == 0) {
        float a0 = 0, a1 = 0, a2 = 0, a3 = 0, a4 = 0;
#pragma unroll
        for (int w2 = 0; w2 < 4; w2++) {
            a0 += red[w2 * 5 + 0]; a1 += red[w2 * 5 + 1];
            a2 += red[w2 * 5 + 2]; a3 += red[w2 * 5 + 3];
            a4 += red[w2 * 5 + 4];
        }
        ws[2048 + bid] = a0;   // S
        ws[3072 + bid] = a1;   // Sw
        ws[4096 + bid] = a2;   // Sh
        ws[5120 + bid] = a3;   // Scol
        ws[6144 + bid] = a4;   // Srow
    }
}

// ---------------- Kernel 2: channel-major per-pixel (value,channel) max -----
// Block = (b, 16-row tile, 32-channel half). x double-buffered per channel.
// Plain stores to this half's private maxbuf: no atomics, no init needed.
__global__ __launch_bounds__(512) void k_maxch(
    const float* __restrict__ x,
    const float* __restrict__ w_bbx, const float* __restrict__ w_width,
    const float* __restrict__ w_width_sh, const float* __restrict__ w_height,
    const float* __restrict__ w_height_sh,
    const float* __restrict__ ws, unsigned long long* __restrict__ mb) {
    __shared__ float4 xs4[2][SROWS * SR4];   // 2 x 14976 B = 29.9 KiB
    int t = blockIdx.x;                      // row tile 0..7
    int half = blockIdx.y;                   // channel half 0..1
    int b = blockIdx.z;
    int tid = threadIdx.x;
    int r = tid >> 5, q = tid & 31;          // r 0..15 (row), q 0..31 (col4)

    // zero both buffers once (pads stay zero forever; interiors restaged)
    for (int j = tid; j < 2 * SROWS * SR4; j += 512)
        ((float4*)xs4)[j] = make_float4(0.f, 0.f, 0.f, 0.f);

    int cbase = half * 32;
    // stage channel cbase into buf 0
    {
        const float* xp = x + (size_t)(b * 64 + cbase) * PLANE;
        for (int j = tid; j < SROWS * 32; j += 512) {
            int i = j >> 5, c4 = j & 31;
            int gr = t * 16 - 5 + i;
            float4 v = make_float4(0.f, 0.f, 0.f, 0.f);
            if ((unsigned)gr < 128u) v = ((const float4*)xp)[gr * 32 + c4];
            xs4[0][i * SR4 + 2 + c4] = v;
        }
    }
    unsigned long long kW[4], kH[4], kS[4];
#pragma unroll
    for (int j = 0; j < 4; j++) { kW[j] = 0ull; kH[j] = 0ull; kS[j] = 0ull; }

    int cur = 0;
    for (int cc = 0; cc < 32; cc++) {
        __syncthreads();                     // buf[cur] staged & visible
        int c = cbase + cc;
        // prefetch next channel into registers (latency hides under compute)
        float4 p0 = make_float4(0.f, 0.f, 0.f, 0.f);
        float4 p1 = make_float4(0.f, 0.f, 0.f, 0.f);
        bool have = (cc + 1 < 32);
        if (have) {
            const float* xp = x + (size_t)(b * 64 + c + 1) * PLANE;
            int i0 = tid >> 5, c40 = tid & 31;
            int gr0 = t * 16 - 5 + i0;
            if ((unsigned)gr0 < 128u) p0 = ((const float4*)xp)[gr0 * 32 + c40];
            if (tid < 320) {
                int gr1 = gr0 + 16;
                if ((unsigned)gr1 < 128u) p1 = ((const float4*)xp)[gr1 * 32 + c40];
            }
        }
        // block-uniform per-channel coefficients (scalar loads, cached)
        float wkc[11], hkc[11];
#pragma unroll
        for (int k = 0; k < 11; k++) {
            wkc[k] = w_width[c * 11 + k];
            hkc[k] = w_height[c * 11 + k];
        }
        float cb = w_bbx[c];
        float cw = 128.0f * w_width_sh[c] * cb;
        float chs = 128.0f * w_height_sh[c] * cb;
        float M = ws[b * 64 + c];

        // vertical 11-tap conv on this thread's 4 columns
        float4 vx;
        float hx = 0.f, hy = 0.f, hz = 0.f, hw = 0.f;
#pragma unroll
        for (int k = 0; k < 11; k++) {
            float4 v = xs4[cur][(r + k) * SR4 + 2 + q];
            if (k == 5) vx = v;
            hx += v.x * hkc[k]; hy += v.y * hkc[k];
            hz += v.z * hkc[k]; hw += v.w * hkc[k];
        }
        // horizontal 11-tap window
        float wbuf[20];
        {
            float4 a0 = xs4[cur][(r + 5) * SR4 + q + 0];
            float4 a1 = xs4[cur][(r + 5) * SR4 + q + 1];
            float4 a3 = xs4[cur][(r + 5) * SR4 + q + 3];
            float4 a4 = xs4[cur][(r + 5) * SR4 + q + 4];
            wbuf[0] = a0.x;  wbuf[1] = a0.y;  wbuf[2] = a0.z;  wbuf[3] = a0.w;
            wbuf[4] = a1.x;  wbuf[5] = a1.y;  wbuf[6] = a1.z;  wbuf[7] = a1.w;
            wbuf[8] = vx.x;  wbuf[9] = vx.y;  wbuf[10] = vx.z; wbuf[11] = vx.w;
            wbuf[12] = a3.x; wbuf[13] = a3.y; wbuf[14] = a3.z; wbuf[15] = a3.w;
            wbuf[16] = a4.x; wbuf[17] = a4.y; wbuf[18] = a4.z; wbuf[19] = a4.w;
        }
        float wo[4];
#pragma unroll
        for (int j = 0; j < 4; j++) {
            float acc = 0.f;
#pragma unroll
            for (int k = 0; k < 11; k++) acc += wbuf[j + 3 + k] * wkc[k];
            wo[j] = acc * cw;
        }
        float ho[4] = {hx * chs, hy * chs, hz * chs, hw * chs};
        float xv[4] = {vx.x, vx.y, vx.z, vx.w};
#pragma unroll
        for (int j = 0; j < 4; j++) {
            float sx = 1.0f / (1.0f + expf(-xv[j]));
            float sc = (sx > M) ? xv[j] : 0.0f;
            unsigned long long cand;
            cand = ((unsigned long long)enc32(sc) << 32) | (unsigned)c;
            if (cand > kS[j]) kS[j] = cand;
            cand = ((unsigned long long)enc32(wo[j]) << 32) | (unsigned)c;
            if (cand > kW[j]) kW[j] = cand;
            cand = ((unsigned long long)enc32(ho[j]) << 32) | (unsigned)c;
            if (cand > kH[j]) kH[j] = cand;
        }
        if (have) {
            xs4[cur ^ 1][(tid >> 5) * SR4 + 2 + (tid & 31)] = p0;
            if (tid < 320)
                xs4[cur ^ 1][((tid >> 5) + 16) * SR4 + 2 + (tid & 31)] = p1;
        }
        cur ^= 1;
    }
    // plain coalesced key stores to this half's private buffer
    int gr = t * 16 + r;
    size_t pix = (size_t)gr * 128 + 4 * q;
    unsigned long long* o = mb + (size_t)half * MBN;
    size_t i0 = (size_t)(b * 3 + 0) * 16384 + pix;   // score
    size_t i1 = (size_t)(b * 3 + 1) * 16384 + pix;   // w
    size_t i2 = (size_t)(b * 3 + 2) * 16384 + pix;   // h
#pragma unroll
    for (int j = 0; j < 4; j++) {
        o[i0 + j] = kS[j];
        o[i1 + j] = kW[j];
        o[i2 + j] = kH[j];
    }
}

// ---------------- Kernel 3: dense masked write (write-only stream) ----------
__global__ __launch_bounds__(256) void k_scatter(
    const unsigned long long* __restrict__ mb, float* __restrict__ out) {
    int chunk = blockIdx.x;                 // 0..15 (1024-pixel chunk)
    int f = blockIdx.y;                     // 0..2
    int b = blockIdx.z;                     // 0..15
    int tid = threadIdx.x;
    size_t pix = (size_t)chunk * 1024 + tid * 4;
    size_t ki = (size_t)(b * 3 + f) * 16384 + pix;
    const unsigned long long* m0 = mb;
    const unsigned long long* m1 = mb + MBN;
    float val[4];
    int win[4];
#pragma unroll
    for (int j = 0; j < 4; j++) {
        unsigned long long k0 = m0[ki + j], k1 = m1[ki + j];
        unsigned long long k = (k0 > k1) ? k0 : k1;
        val[j] = dec32((unsigned)(k >> 32));
        win[j] = (int)(k & 63u);
    }
    float* ob = out + (size_t)(b * 192 + f * 64) * PLANE + pix;
#pragma unroll
    for (int c = 0; c < 64; c++) {
        float4 o;
        o.x = (win[0] == c) ? val[0] : 0.f;
        o.y = (win[1] == c) ? val[1] : 0.f;
        o.z = (win[2] == c) ? val[2] : 0.f;
        o.w = (win[3] == c) ? val[3] : 0.f;
        *(float4*)&ob[(size_t)c * PLANE] = o;
    }
}

// ---------------- Kernel 4: bbox rows ----------------
__global__ __launch_bounds__(256) void k_bbox(const float* __restrict__ ws,
                                              float* __restrict__ out) {
    int idx = blockIdx.x * 256 + threadIdx.x;
    if (idx >= 1024) return;
    int b = idx >> 6;
    float S    = ws[2048 + idx];
    float Sw   = ws[3072 + idx];
    float Sh   = ws[4096 + idx];
    float Scol = ws[5120 + idx];
    float Srow = ws[6144 + idx];
    float ps   = ws[1024 + idx];
    float inv = 1.0f / S;
    float wsv = Sw * inv, hsv = Sh * inv;
    float x1 = Scol * inv - 0.5f * wsv;
    float y1 = Srow * inv - 0.5f * hsv;
    float* o = out + OUT0 + (size_t)idx * 6;
    o[0] = (float)b;
    o[1] = x1;
    o[2] = y1;
    o[3] = x1 + wsv;
    o[4] = y1 + hsv;
    o[5] = ps;
}

extern "C" void kernel_launch(void* const* d_in, const int* in_sizes, int n_in,
                              void* d_out, int out_size, void* d_ws, size_t ws_size,
                              hipStream_t stream) {
    const float* x          = (const float*)d_in[0];
    const float* w_bbx      = (const float*)d_in[1];
    const float* w_width    = (const float*)d_in[2];
    const float* w_width_sh = (const float*)d_in[3];
    const float* w_height   = (const float*)d_in[4];
    const float* w_height_sh= (const float*)d_in[5];
    float* out = (float*)d_out;
    float* ws  = (float*)d_ws;
    unsigned long long* mb = (unsigned long long*)(ws + MBOFF);

    k_stats<<<dim3(1024), dim3(256), 0, stream>>>(
        x, w_bbx, w_width, w_width_sh, w_height, w_height_sh, ws);
    k_maxch<<<dim3(8, 2, 16), dim3(512), 0, stream>>>(
        x, w_bbx, w_width, w_width_sh, w_height, w_height_sh, ws, mb);
    k_scatter<<<dim3(16, 3, 16), dim3(256), 0, stream>>>(mb, out);
    k_bbox<<<dim3(4), dim3(256), 0, stream>>>(ws, out);
}